// Round 7
// baseline (66.295 us; speedup 1.0000x reference)
//
#include <hip/hip_runtime.h>
#include <math.h>

#define B_ 8
#define C_ 64
#define K_ 32
#define HW_ 16384
#define SROW 36              // padded LDS row stride (floats): +1 bank-quad per row
#define NPART_ 256           // partial slabs per batch (one per wave-task)
#define TILE_ 256            // fusion px tile
#define NEG_SLOPE_ 0.1f

// ws layout:
//   [0, 33.6MB)           float partial[B_][NPART_][C_][C_]
//   [33.6MB, +64KB)       int   idxb[B_][C_][K_]

// corr v3: 8x8 register tile per thread (16 b128 reads per 256 fma).
// Each wave privately stages a 64x32-n slab (no block barriers), processes
// 2 sub-chunks (64 n) into one f32 partial slab.
__global__ __launch_bounds__(256, 2) void corr_partial_kernel(
    const float* __restrict__ LR, const float* __restrict__ HR,
    float* __restrict__ partial)
{
    __shared__ float lrS[4][C_][SROW];   // 36.9 KB
    __shared__ float hrS[4][C_][SROW];   // 36.9 KB
    const int bid = blockIdx.x;          // 512 = B * 64
    const int b = bid >> 6;
    const int q = bid & 63;
    const int t = threadIdx.x;
    const int wv = t >> 6;
    const int lane = t & 63;
    const int cq = lane >> 3;            // 0..7
    const int dq = lane & 7;             // 0..7

    float acc[8][8] = {};

    #pragma unroll 1
    for (int s = 0; s < 2; ++s) {
        const int n0 = (((q * 4 + wv) << 1) + s) * 32;
        // stage this wave's 64x32 slabs (wave-private; compiler orders LDS WAR)
        #pragma unroll
        for (int i = 0; i < 8; ++i) {
            const int c = i * 8 + (lane >> 3);
            const int col = (lane & 7) * 4;
            *reinterpret_cast<float4*>(&lrS[wv][c][col]) =
                *reinterpret_cast<const float4*>(&LR[(size_t)(b * C_ + c) * HW_ + n0 + col]);
            *reinterpret_cast<float4*>(&hrS[wv][c][col]) =
                *reinterpret_cast<const float4*>(&HR[(size_t)(b * C_ + c) * HW_ + n0 + col]);
        }
        // compute: rows cq+8i / dq+8j; stride 36 -> 8 broadcast groups on
        // 8 distinct bank-quads per read instruction (conflict-free)
        #pragma unroll 2
        for (int nq = 0; nq < 8; ++nq) {
            float4 lv[8], hv[8];
            #pragma unroll
            for (int i = 0; i < 8; ++i)
                lv[i] = *reinterpret_cast<const float4*>(&lrS[wv][cq + 8 * i][nq * 4]);
            #pragma unroll
            for (int j = 0; j < 8; ++j)
                hv[j] = *reinterpret_cast<const float4*>(&hrS[wv][dq + 8 * j][nq * 4]);
            #pragma unroll
            for (int i = 0; i < 8; ++i)
                #pragma unroll
                for (int j = 0; j < 8; ++j) {
                    acc[i][j] = fmaf(lv[i].x, hv[j].x, acc[i][j]);
                    acc[i][j] = fmaf(lv[i].y, hv[j].y, acc[i][j]);
                    acc[i][j] = fmaf(lv[i].z, hv[j].z, acc[i][j]);
                    acc[i][j] = fmaf(lv[i].w, hv[j].w, acc[i][j]);
                }
        }
    }

    const int pid = q * 4 + wv;
    float* P = partial + (size_t)(b * NPART_ + pid) * (C_ * C_);
    #pragma unroll
    for (int i = 0; i < 8; ++i)
        #pragma unroll
        for (int j = 0; j < 8; ++j)
            P[(cq + 8 * i) * C_ + (dq + 8 * j)] = acc[i][j];
}

// Reduce 256 partials per (b,c) in fixed order (f64, deterministic),
// rank channels like lax.top_k (stable descending), emit indices.
__global__ __launch_bounds__(256) void rank_kernel(
    const float* __restrict__ partial, int* __restrict__ idxb)
{
    __shared__ double sh[4][C_];
    __shared__ double vals[C_];
    const int blk = blockIdx.x;     // b*64 + c
    const int b = blk >> 6;
    const int c = blk & 63;
    const int g = threadIdx.x >> 6;
    const int d = threadIdx.x & 63;

    double acc = 0.0;
    for (int k = 0; k < 64; ++k)
        acc += (double)partial[(size_t)(b * NPART_ + g * 64 + k) * (C_ * C_) + c * C_ + d];
    sh[g][d] = acc;
    __syncthreads();

    if (threadIdx.x < 64) {
        vals[d] = ((sh[0][d] + sh[1][d]) + sh[2][d]) + sh[3][d];
    }
    __syncthreads();

    if (threadIdx.x < 64) {
        const double vd = vals[d];
        int r = 0;
        for (int j = 0; j < C_; ++j) {
            const double vj = vals[j];
            r += (int)((vj > vd) || (vj == vd && j < d));   // stable descending rank
        }
        if (r < K_) idxb[blk * K_ + r] = d;
    }
}

// Gather fusion (unchanged from round 6): stage HR[64][256] px-slab in LDS;
// each wave owns a c-quarter, gathers ds_read_b128 (1 KB/wave-instr).
__global__ __launch_bounds__(256, 2) void fusion_gather_kernel(
    const float* __restrict__ HR, const float* __restrict__ LR,
    const int* __restrict__ idxb,
    const float* __restrict__ w1, const float* __restrict__ b1,
    const float* __restrict__ w2, const float* __restrict__ b2,
    float* __restrict__ out)
{
    __shared__ float hrS[C_][TILE_];   // 64 KB

    const int t = threadIdx.x;
    const int bid = blockIdx.x;        // 512 = B * (HW/TILE)
    const int b = bid >> 6;
    const int px0 = (bid & 63) * TILE_;

    const float* HRb = HR + (size_t)b * C_ * HW_;
    #pragma unroll
    for (int i = 0; i < 16; ++i) {
        const int f = i * 256 + t;
        const int c = f >> 6;
        const int q = f & 63;
        *reinterpret_cast<float4*>(&hrS[c][q * 4]) =
            *reinterpret_cast<const float4*>(&HRb[(size_t)c * HW_ + px0 + q * 4]);
    }
    __syncthreads();

    const int wv = t >> 6;             // wave id -> c-quarter
    const int lane = t & 63;
    const int p4 = lane * 4;           // this lane's 4 px within the tile

    const int* idxc = idxb + b * C_ * K_;
    const float w10 = w1[0];
    const float b1v = b1[0], w2v = w2[0], b2v = b2[0];

    #pragma unroll 1
    for (int ci = 0; ci < 16; ++ci) {
        const int c = wv * 16 + ci;
        const float4 l4 = *reinterpret_cast<const float4*>(
            &LR[(size_t)(b * C_ + c) * HW_ + px0 + p4]);         // issue early
        float acc[4] = {0.f, 0.f, 0.f, 0.f};
        float mx[4]  = {-1e30f, -1e30f, -1e30f, -1e30f};
        #pragma unroll
        for (int k = 0; k < K_; ++k) {
            const int d = idxc[c * K_ + k];          // uniform -> s_load
            const float4 h = *reinterpret_cast<const float4*>(&hrS[d][p4]);
            const float wk = w1[k + 1];              // uniform -> SGPR
            acc[0] = fmaf(h.x, wk, acc[0]);
            acc[1] = fmaf(h.y, wk, acc[1]);
            acc[2] = fmaf(h.z, wk, acc[2]);
            acc[3] = fmaf(h.w, wk, acc[3]);
            mx[0] = fmaxf(mx[0], h.x);
            mx[1] = fmaxf(mx[1], h.y);
            mx[2] = fmaxf(mx[2], h.z);
            mx[3] = fmaxf(mx[3], h.w);
        }
        const float l[4] = {l4.x, l4.y, l4.z, l4.w};
        float o[4];
        #pragma unroll
        for (int p = 0; p < 4; ++p) {
            float f = fmaf(w10, l[p], acc[p]) + b1v;
            f = f >= 0.f ? f : NEG_SLOPE_ * f;
            f = fmaf(w2v, f, b2v);
            const float s = 1.f / (1.f + __expf(-mx[p]));
            o[p] = f * (1.f + s);
        }
        *reinterpret_cast<float4*>(&out[(size_t)(b * C_ + c) * HW_ + px0 + p4]) =
            make_float4(o[0], o[1], o[2], o[3]);
    }
}

extern "C" void kernel_launch(void* const* d_in, const int* in_sizes, int n_in,
                              void* d_out, int out_size, void* d_ws, size_t ws_size,
                              hipStream_t stream)
{
    const float* HR = (const float*)d_in[0];
    const float* LR = (const float*)d_in[1];
    const float* w1 = (const float*)d_in[2];
    const float* b1 = (const float*)d_in[3];
    const float* w2 = (const float*)d_in[4];
    const float* b2 = (const float*)d_in[5];
    float* out = (float*)d_out;

    float* partial = (float*)d_ws;
    int* idxb = (int*)((char*)d_ws + (size_t)B_ * NPART_ * C_ * C_ * sizeof(float));

    corr_partial_kernel<<<B_ * 64, 256, 0, stream>>>(LR, HR, partial);
    rank_kernel<<<B_ * C_, 256, 0, stream>>>(partial, idxb);
    fusion_gather_kernel<<<B_ * (HW_ / TILE_), 256, 0, stream>>>(HR, LR, idxb, w1, b1, w2, b2, out);
}

// Round 8
// 60.398 us; speedup vs baseline: 1.0976x; 1.0976x over previous
//
#include <hip/hip_runtime.h>
#include <math.h>

#define B_ 8
#define C_ 64
#define K_ 32
#define HW_ 16384
#define LDN 132              // padded staging row stride (floats): +1 bank-quad per row
#define NCHUNKOUT_ 64        // one partial slab per block (256 n each)
#define TILE_ 256            // fusion px tile
#define NEG_SLOPE_ 0.1f

// ws layout:
//   [0, 8MB)          float partial[B_][NCHUNKOUT_][C_][C_]
//   [8MB, 8MB+64KB)   int   idxb[B_][C_][K_]

// corr v4: block stages 64x128-n (both arrays); each of 4 waves computes the
// full 64x64 output over its private 32-n slice with an 8x8 register tile
// (16 b128 reads per 256 fma = 16:1 fma:read). After 2 rounds (256 n/block),
// the 4 wave-partials are reduced in-LDS -> one f32 slab per block.
__global__ __launch_bounds__(256, 2) void corr_partial_kernel(
    const float* __restrict__ LR, const float* __restrict__ HR,
    float* __restrict__ partial)
{
    __shared__ float smem[16896];        // 67584 B; staging, then reduction scratch
    float* lrS = smem;                   // [c][LDN]
    float* hrS = smem + C_ * LDN;        // 8448 floats in

    const int bid = blockIdx.x;          // 512 = B * 64
    const int b = bid >> 6;
    const int q = bid & 63;
    const int t = threadIdx.x;
    const int wv = t >> 6;
    const int lane = t & 63;
    const int cq = lane >> 3;            // 0..7
    const int dq = lane & 7;             // 0..7

    float acc[8][8] = {};

    for (int r = 0; r < 2; ++r) {
        const int n0 = q * 256 + r * 128;
        if (r) __syncthreads();          // WAR before restage
        #pragma unroll
        for (int p = 0; p < 8; ++p) {
            const int f = p * 256 + t;
            const int c = f >> 5;
            const int col = (f & 31) * 4;
            *reinterpret_cast<float4*>(&lrS[c * LDN + col]) =
                *reinterpret_cast<const float4*>(&LR[(size_t)(b * C_ + c) * HW_ + n0 + col]);
            *reinterpret_cast<float4*>(&hrS[c * LDN + col]) =
                *reinterpret_cast<const float4*>(&HR[(size_t)(b * C_ + c) * HW_ + n0 + col]);
        }
        __syncthreads();

        // wave wv owns n-columns [wv*32, wv*32+32) of the staged 128
        #pragma unroll 2
        for (int nq = 0; nq < 8; ++nq) {
            const int col = wv * 32 + nq * 4;
            float4 lv[8];
            #pragma unroll
            for (int i = 0; i < 8; ++i)
                lv[i] = *reinterpret_cast<const float4*>(&lrS[(cq + 8 * i) * LDN + col]);
            #pragma unroll
            for (int j = 0; j < 8; ++j) {
                const float4 hv = *reinterpret_cast<const float4*>(&hrS[(dq + 8 * j) * LDN + col]);
                #pragma unroll
                for (int i = 0; i < 8; ++i) {
                    acc[i][j] = fmaf(lv[i].x, hv.x, acc[i][j]);
                    acc[i][j] = fmaf(lv[i].y, hv.y, acc[i][j]);
                    acc[i][j] = fmaf(lv[i].z, hv.z, acc[i][j]);
                    acc[i][j] = fmaf(lv[i].w, hv.w, acc[i][j]);
                }
            }
        }
    }

    // in-block reduction: red[w][p][lane], p = i*8+j (conflict-free b32 columns)
    __syncthreads();
    float* red = smem;                   // 4*64*64 floats = 65536 B <= 67584
    #pragma unroll
    for (int i = 0; i < 8; ++i)
        #pragma unroll
        for (int j = 0; j < 8; ++j)
            red[(wv * 64 + i * 8 + j) * 64 + lane] = acc[i][j];
    __syncthreads();

    // thread (wv,lane): sum positions p in [wv*16, wv*16+16) at this lane,
    // fixed order w=0..3 (deterministic), scatter to the block's slab.
    float* P = partial + (size_t)bid * (C_ * C_);
    #pragma unroll
    for (int pp = 0; pp < 16; ++pp) {
        const int p = wv * 16 + pp;
        const float s = ((red[(0 * 64 + p) * 64 + lane]
                        + red[(1 * 64 + p) * 64 + lane])
                        + red[(2 * 64 + p) * 64 + lane])
                        + red[(3 * 64 + p) * 64 + lane];
        const int row = cq + 8 * (p >> 3);
        const int col = dq + 8 * (p & 7);
        P[row * C_ + col] = s;
    }
}

// Reduce partials (f64, deterministic), rank channels per (b,c) like lax.top_k
// (stable descending), emit top-K channel indices.  (round-6 version)
__global__ __launch_bounds__(64) void rank_kernel(
    const float* __restrict__ partial, int* __restrict__ idxb)
{
    __shared__ double vals[C_];
    const int blk = blockIdx.x;     // b*64 + c
    const int b = blk >> 6;
    const int c = blk & 63;
    const int d = threadIdx.x;

    double acc = 0.0;
    for (int k = 0; k < NCHUNKOUT_; ++k)
        acc += (double)partial[(size_t)(b * NCHUNKOUT_ + k) * (C_ * C_) + c * C_ + d];
    vals[d] = acc;
    __syncthreads();

    int r = 0;
    for (int jj = 0; jj < C_; ++jj) {
        const double vj = vals[jj];
        r += (int)((vj > acc) || (vj == acc && jj < d));   // stable descending rank
    }
    if (r < K_) idxb[blk * K_ + r] = d;
}

// Gather fusion v3: same b128-gather structure as round 6, but 512-thread
// blocks (8 waves, 8 c each) -> 16 waves/CU to saturate the DS pipe.
__global__ __launch_bounds__(512, 4) void fusion_gather_kernel(
    const float* __restrict__ HR, const float* __restrict__ LR,
    const int* __restrict__ idxb,
    const float* __restrict__ w1, const float* __restrict__ b1,
    const float* __restrict__ w2, const float* __restrict__ b2,
    float* __restrict__ out)
{
    __shared__ float hrS[C_][TILE_];   // 64 KB

    const int t = threadIdx.x;
    const int bid = blockIdx.x;        // 512 = B * (HW/TILE)
    const int b = bid >> 6;
    const int px0 = (bid & 63) * TILE_;

    const float* HRb = HR + (size_t)b * C_ * HW_;
    #pragma unroll
    for (int i = 0; i < 8; ++i) {
        const int f = i * 512 + t;
        const int c = f >> 6;
        const int qq = f & 63;
        *reinterpret_cast<float4*>(&hrS[c][qq * 4]) =
            *reinterpret_cast<const float4*>(&HRb[(size_t)c * HW_ + px0 + qq * 4]);
    }
    __syncthreads();

    const int wv = t >> 6;             // wave id -> c-octant
    const int lane = t & 63;
    const int p4 = lane * 4;           // this lane's 4 px within the tile

    const int* idxc = idxb + b * C_ * K_;
    const float w10 = w1[0];
    const float b1v = b1[0], w2v = w2[0], b2v = b2[0];

    #pragma unroll 1
    for (int ci = 0; ci < 8; ++ci) {
        const int c = wv * 8 + ci;
        const float4 l4 = *reinterpret_cast<const float4*>(
            &LR[(size_t)(b * C_ + c) * HW_ + px0 + p4]);         // issue early
        float acc[4] = {0.f, 0.f, 0.f, 0.f};
        float mx[4]  = {-1e30f, -1e30f, -1e30f, -1e30f};
        #pragma unroll
        for (int k = 0; k < K_; ++k) {
            const int d = idxc[c * K_ + k];          // uniform -> s_load
            const float4 h = *reinterpret_cast<const float4*>(&hrS[d][p4]);
            const float wk = w1[k + 1];              // uniform -> SGPR
            acc[0] = fmaf(h.x, wk, acc[0]);
            acc[1] = fmaf(h.y, wk, acc[1]);
            acc[2] = fmaf(h.z, wk, acc[2]);
            acc[3] = fmaf(h.w, wk, acc[3]);
            mx[0] = fmaxf(mx[0], h.x);
            mx[1] = fmaxf(mx[1], h.y);
            mx[2] = fmaxf(mx[2], h.z);
            mx[3] = fmaxf(mx[3], h.w);
        }
        const float l[4] = {l4.x, l4.y, l4.z, l4.w};
        float o[4];
        #pragma unroll
        for (int p = 0; p < 4; ++p) {
            float f = fmaf(w10, l[p], acc[p]) + b1v;
            f = f >= 0.f ? f : NEG_SLOPE_ * f;
            f = fmaf(w2v, f, b2v);
            const float s = 1.f / (1.f + __expf(-mx[p]));
            o[p] = f * (1.f + s);
        }
        *reinterpret_cast<float4*>(&out[(size_t)(b * C_ + c) * HW_ + px0 + p4]) =
            make_float4(o[0], o[1], o[2], o[3]);
    }
}

extern "C" void kernel_launch(void* const* d_in, const int* in_sizes, int n_in,
                              void* d_out, int out_size, void* d_ws, size_t ws_size,
                              hipStream_t stream)
{
    const float* HR = (const float*)d_in[0];
    const float* LR = (const float*)d_in[1];
    const float* w1 = (const float*)d_in[2];
    const float* b1 = (const float*)d_in[3];
    const float* w2 = (const float*)d_in[4];
    const float* b2 = (const float*)d_in[5];
    float* out = (float*)d_out;

    float* partial = (float*)d_ws;
    int* idxb = (int*)((char*)d_ws + (size_t)B_ * NCHUNKOUT_ * C_ * C_ * sizeof(float));

    corr_partial_kernel<<<B_ * 64, 256, 0, stream>>>(LR, HR, partial);
    rank_kernel<<<B_ * C_, 64, 0, stream>>>(partial, idxb);
    fusion_gather_kernel<<<B_ * (HW_ / TILE_), 512, 0, stream>>>(HR, LR, idxb, w1, b1, w2, b2, out);
}